// Round 3
// baseline (288.240 us; speedup 1.0000x reference)
//
#include <hip/hip_runtime.h>

#define B_TOTAL 2000000
#define PAD 21      // 21 coprime with 32 banks -> conflict-free LDS transpose writes
#define NBLK 512    // exactly 2 resident blocks/CU -> ~10K concurrent read windows chip-wide
#define NTILES 7813 // ceil(2e6/256); last tile has 128 valid cols

// POLLU RHS: 25 fluxes, 20 species.
// conc: [20, B] species-major; out: [B, 20].
// v4: DRAM-scheduling experiment. 512 persistent-ish blocks, each walking a
//     CONTIGUOUS span of ~15 256-col tiles with a register double-buffer
//     (prefetch tile n+1's 20 dword loads before computing tile n; first use
//     of the prefetch regs is at loop end, so loads stay in flight across
//     compute + LDS transpose + store sweep). Load/store plumbing = v1
//     (proven equal to wide-load variants): dword loads, LDS transpose,
//     dense float4 store sweep.
__global__ __launch_bounds__(256) void pollu_kernel(
    const float* __restrict__ conc,
    const float* __restrict__ k,
    float* __restrict__ out)
{
    __shared__ float lds[256 * PAD];  // 21504 B

    const int t = threadIdx.x;
    const int blk = blockIdx.x;

    // Contiguous tile span per block: q=15, r=133 blocks get one extra.
    const int q = NTILES / NBLK;       // 15
    const int r = NTILES - q * NBLK;   // 133
    const int t0 = blk * q + (blk < r ? blk : r);
    const int t1 = t0 + q + (blk < r ? 1 : 0);

    // k is uniform + constant-indexed -> scalar (SGPR) loads.
    const float k0 = k[0],  k1 = k[1],  k2 = k[2],  k3 = k[3],  k4 = k[4];
    const float k5 = k[5],  k6 = k[6],  k7 = k[7],  k8 = k[8],  k9 = k[9];
    const float k10 = k[10], k11 = k[11], k12 = k[12], k13 = k[13], k14 = k[14];
    const float k15 = k[15], k16 = k[16], k17 = k[17], k18 = k[18], k19 = k[19];
    const float k20 = k[20], k21 = k[21], k22 = k[22], k23 = k[23], k24 = k[24];

// Compute 25 fluxes from C(s), then overwrite C(s) with dy[s].
// Safe in-place: every C read happens in the flux block, before any C write.
#define POLLU_FLUX_DY(C)                                                      \
        const float f1  = k0  * C(0);                                         \
        const float f2  = k1  * C(1)  * C(3);                                 \
        const float f3  = k2  * C(4)  * C(1);                                 \
        const float f4  = k3  * C(6);                                         \
        const float f5  = k4  * C(6);                                         \
        const float f6  = k5  * C(6)  * C(5);                                 \
        const float f7  = k6  * C(8);                                         \
        const float f8  = k7  * C(8)  * C(5);                                 \
        const float f9  = k8  * C(10) * C(1);                                 \
        const float f10 = k9  * C(10) * C(0);                                 \
        const float f11 = k10 * C(12);                                        \
        const float f12 = k11 * C(9)  * C(1);                                 \
        const float f13 = k12 * C(13);                                        \
        const float f14 = k13 * C(0)  * C(5);                                 \
        const float f15 = k14 * C(2);                                         \
        const float f16 = k15 * C(3);                                         \
        const float f17 = k16 * C(3);                                         \
        const float f18 = k17 * C(15);                                        \
        const float f19 = k18 * C(15);                                        \
        const float f20 = k19 * C(16) * C(5);                                 \
        const float f21 = k20 * C(18);                                        \
        const float f22 = k21 * C(18);                                        \
        const float f23 = k22 * C(0)  * C(3);                                 \
        const float f24 = k23 * C(18) * C(0);                                 \
        const float f25 = k24 * C(19);                                        \
        C(0)  = -f1 - f10 - f14 - f23 - f24 + f2 + f3 + f9 + f11 + f12 + f22 + f25; \
        C(1)  = -f2 - f3 - f9 - f12 + f1 + f21;                               \
        C(2)  = -f15 + f1 + f17 + f19 + f22;                                  \
        C(3)  = -f2 - f16 - f17 - f23 + f15;                                  \
        C(4)  = -f3 + 2.0f * f4 + f6 + f7 + f13 + f20;                        \
        C(5)  = -f6 - f8 - f14 - f20 + f3 + 2.0f * f18;                       \
        C(6)  = -f4 - f5 - f6 + f13;                                          \
        C(7)  =  f4 + f5 + f6 + f7;                                           \
        C(8)  = -f7 - f8;                                                     \
        C(9)  = -f12 + f7 + f9;                                               \
        C(10) = -f9 - f10 + f8 + f11;                                         \
        C(11) =  f9;                                                          \
        C(12) = -f11 + f10;                                                   \
        C(13) = -f13 + f12;                                                   \
        C(14) =  f14;                                                         \
        C(15) = -f18 - f19 + f16;                                             \
        C(16) = -f20;                                                         \
        C(17) =  f20;                                                         \
        C(18) = -f21 - f22 - f24 + f23 + f25;                                 \
        C(19) = -f25 + f24;

#define CC(s) cc[s]

    float cc[20], cn[20];

    // Prologue: load first tile into cc.
    {
        const int col = t0 * 256 + t;
        if (col < B_TOTAL) {
#pragma unroll
            for (int s = 0; s < 20; ++s) cc[s] = conc[(size_t)s * B_TOTAL + (size_t)col];
        } else {
#pragma unroll
            for (int s = 0; s < 20; ++s) cc[s] = 0.0f;
        }
    }

    float4* outv = (float4*)out;

    for (int tt = t0; tt < t1; ++tt) {
        const bool hasNext = (tt + 1 < t1);  // block-uniform
        if (hasNext) {
            // Issue next tile's 20 loads NOW; first use is the cc=cn copy at
            // loop end -> loads overlap compute + transpose + store sweep.
            const int col = (tt + 1) * 256 + t;
            if (col < B_TOTAL) {
#pragma unroll
                for (int s = 0; s < 20; ++s) cn[s] = conc[(size_t)s * B_TOTAL + (size_t)col];
            } else {
#pragma unroll
                for (int s = 0; s < 20; ++s) cn[s] = 0.0f;
            }
        }

        // Compute: dy overwrites cc in place.
        { POLLU_FLUX_DY(CC) }

        __syncthreads();  // previous iteration's LDS reads complete
#pragma unroll
        for (int s = 0; s < 20; ++s) lds[t * PAD + s] = cc[s];
        __syncthreads();

        // Dense store sweep: tile covers nvalid*5 float4s, contiguous in out.
        const int nvalid = min(256, B_TOTAL - tt * 256);
        const int nF4 = nvalid * 5;
        const int baseF4 = tt * 1280;
#pragma unroll
        for (int i = 0; i < 5; ++i) {
            const int J = i * 256 + t;
            if (J < nF4) {
                const int q2 = J / 5;        // tile-local column
                const int r2 = 4 * (J % 5);  // starting species
                const float* p = &lds[q2 * PAD + r2];
                outv[baseF4 + J] = make_float4(p[0], p[1], p[2], p[3]);
            }
        }

        if (hasNext) {
#pragma unroll
            for (int s = 0; s < 20; ++s) cc[s] = cn[s];
        }
    }
}

extern "C" void kernel_launch(void* const* d_in, const int* in_sizes, int n_in,
                              void* d_out, int out_size, void* d_ws, size_t ws_size,
                              hipStream_t stream) {
    // d_in[0] = t (unused), d_in[1] = conc_in [20, B], d_in[2] = k [25]
    const float* conc = (const float*)d_in[1];
    const float* k    = (const float*)d_in[2];
    float* out        = (float*)d_out;

    pollu_kernel<<<NBLK, 256, 0, stream>>>(conc, k, out);
}